// Round 8
// baseline (63.736 us; speedup 1.0000x reference)
//
#include <hip/hip_runtime.h>

#define BB 16
#define NN 128
#define DD 128

// K1: partial[blk][j',d] = sum_{i in chunk} adj[b,i,j]*e[b,i,j,d]
// blk = b*64 + ic*2 + jh : i-chunk of 4, j-half of 64. The block reads
// e[b, i0..i0+4, j0..j0+64, :] = 4 x 32KB FULLY CONTIGUOUS spans (1-KB
// wave-loads), accumulates in 8 float4 registers/thread (no LDS RMW),
// writes a coalesced 32-KB partial tile. 1024 blocks = 4/CU.
// Side job (first 320 blocks): float4-interleaved weight transposes.
__global__ __launch_bounds__(256) void stage1_kernel(
    const float* __restrict__ e, const float* __restrict__ adj,
    float* __restrict__ partial,
    const float* __restrict__ Wm, const float* __restrict__ Wu,
    float* __restrict__ WmT4, float* __restrict__ WuT4) {
    const int blk = blockIdx.x;
    const int t = threadIdx.x;

    if (blk < 320) {                     // 320*256 = 384*128 + 256*128
        const int idx = blk * 256 + t;
        if (idx < 384 * 128) {
            const int k = idx / 384, dcol = idx % 384;
            WmT4[((dcol >> 2) * 128 + k) * 4 + (dcol & 3)] = Wm[idx];
        } else {
            const int o = idx - 384 * 128;
            const int k = o / 256, dcol = o % 256;
            WuT4[((dcol >> 2) * 128 + k) * 4 + (dcol & 3)] = Wu[o];
        }
    }

    const int b = blk >> 6, ic = (blk & 63) >> 1, jh = blk & 1;
    const int i0 = ic * 4, j0 = jh * 64;

    __shared__ float adj_s[4][64];
    {
        const int row = t >> 6, col = t & 63;   // 256 = 4x64, coalesced 256-B rows
        adj_s[row][col] = adj[(size_t)(b * NN + i0 + row) * NN + j0 + col];
    }
    __syncthreads();

    const float4* __restrict__ e4 = (const float4*)e;
    float4 acc[8];
    #pragma unroll
    for (int s = 0; s < 8; ++s) acc[s] = make_float4(0.f, 0.f, 0.f, 0.f);

    #pragma unroll
    for (int ii = 0; ii < 4; ++ii) {
        const size_t base = ((size_t)(b * NN + i0 + ii) * NN + j0) * 32;
        #pragma unroll
        for (int s = 0; s < 8; ++s) {
            const int x = s * 256 + t;           // 0..2047 : j' = x>>5, d4 = x&31
            const float4 v = e4[base + x];       // contiguous 1-KB wave-loads
            const float a = adj_s[ii][x >> 5];   // LDS broadcast (2/wave)
            acc[s].x += a * v.x; acc[s].y += a * v.y;
            acc[s].z += a * v.z; acc[s].w += a * v.w;
        }
    }
    float4* __restrict__ p4 = (float4*)partial + (size_t)blk * 2048;
    #pragma unroll
    for (int s = 0; s < 8; ++s) p4[s * 256 + t] = acc[s];   // coalesced 32-KB store
}

// K2: es[b,j,d] = sum_{ic} partial[b,ic,jh(j)][jrel,d].  65536 float4 outputs,
// one per thread; 32 strided-but-coalesced reads each. es aliases d_out.
__global__ __launch_bounds__(256) void stage2_kernel(const float* __restrict__ partial,
                                                     float* __restrict__ es) {
    const int idx = blockIdx.x * 256 + threadIdx.x;   // 0..65535
    const int b = idx >> 12, rem = idx & 4095;
    const int j = rem >> 5, d4 = rem & 31;
    const int jh = j >> 6, jrel = j & 63;
    const float4* __restrict__ p4 = (const float4*)partial;
    const size_t off = (size_t)jrel * 32 + d4;
    float4 s = make_float4(0.f, 0.f, 0.f, 0.f);
    #pragma unroll 8
    for (int ic = 0; ic < 32; ++ic) {
        const float4 v = p4[(size_t)(b * 64 + ic * 2 + jh) * 2048 + off];
        s.x += v.x; s.y += v.y; s.z += v.z; s.w += v.w;
    }
    ((float4*)es)[idx] = s;
}

// K3: fused small GEMMs. Block = (b, 8 j's), 1024 threads (16 waves, 1 block/CU,
// 4 waves/SIMD). Thread slice jl = t>>7 owns one j. Weight reads via WmT4/WuT4
// float4-interleaved (coalesced); 8 j's/block halves weight L2 traffic vs 4.
__global__ __launch_bounds__(1024) void fuse_kernel(
    const float* __restrict__ h, const float* __restrict__ adj,
    const float* __restrict__ es, const float* __restrict__ WmT4,
    const float* __restrict__ bm, const float* __restrict__ WuT4,
    const float* __restrict__ bu, float* __restrict__ out) {
    const int blk = blockIdx.x;
    const int b = blk >> 4;
    const int jbase = (blk & 15) * 8;
    const int t = threadIdx.x;

    __shared__ float adj_s[8][NN];
    __shared__ float h_s[8][DD];
    __shared__ float es_s[8][DD];
    __shared__ float ah_s[8][DD];
    __shared__ float ms_s[8][DD];
    __shared__ float deg_s[8];

    {   // staging: one pass each, 1024 threads
        const int jj = t >> 7, d0 = t & 127;
        h_s[jj][d0]  = h [(size_t)(b * NN + jbase + jj) * DD + d0];
        es_s[jj][d0] = es[(size_t)(b * NN + jbase + jj) * DD + d0];
        const int i = t >> 3, j2 = t & 7;
        adj_s[j2][i] = adj[(size_t)(b * NN + i) * NN + jbase + j2];
    }
    __syncthreads();

    const int k = t & 127, jl = t >> 7;       // jl = 0..7, one j per slice

    if (t < 256) {                            // deg[jj] = sum_i adj[i][jj]
        const int jj = t >> 5, l = t & 31;
        float s = adj_s[jj][l] + adj_s[jj][l + 32] + adj_s[jj][l + 64] + adj_s[jj][l + 96];
        #pragma unroll
        for (int off = 16; off; off >>= 1) s += __shfl_xor(s, off);
        if (l == 0) deg_s[jj] = s;
    }

    // C: ah[jl][k] = sum_i adj[i][jl]*h[b,i,k]  (h coalesced across lanes)
    {
        float a0 = 0.f;
        const float* __restrict__ hp = h + (size_t)b * NN * DD + k;
        #pragma unroll 8
        for (int m = 0; m < 32; ++m) {
            const float4 aA = *(const float4*)&adj_s[jl][4 * m];
            const float h0 = hp[(size_t)(4 * m + 0) * DD];
            const float h1 = hp[(size_t)(4 * m + 1) * DD];
            const float h2 = hp[(size_t)(4 * m + 2) * DD];
            const float h3 = hp[(size_t)(4 * m + 3) * DD];
            a0 += aA.x * h0 + aA.y * h1 + aA.z * h2 + aA.w * h3;
        }
        ah_s[jl][k] = a0;
    }
    __syncthreads();

    // D: msum[jl][k]
    {
        float pa = 0.f, ph = 0.f, pe = 0.f;
        const float4* __restrict__ w1p = (const float4*)WmT4 + k;
        #pragma unroll 4
        for (int q = 0; q < 32; ++q) {
            const float4 w1 = w1p[q * 128];
            const float4 w2 = w1p[(32 + q) * 128];
            const float4 w3 = w1p[(64 + q) * 128];
            const float4 ah4 = *(const float4*)&ah_s[jl][4 * q];
            const float4 h4  = *(const float4*)&h_s[jl][4 * q];
            const float4 e4v = *(const float4*)&es_s[jl][4 * q];
            pa += ah4.x * w1.x + ah4.y * w1.y + ah4.z * w1.z + ah4.w * w1.w;
            ph += h4.x  * w2.x + h4.y  * w2.y + h4.z  * w2.z + h4.w  * w2.w;
            pe += e4v.x * w3.x + e4v.y * w3.y + e4v.z * w3.z + e4v.w * w3.w;
        }
        ms_s[jl][k] = pa + pe + deg_s[jl] * (ph + bm[k]);
    }
    __syncthreads();

    // E: out = h·WuA^T + msum·WuB^T + bu
    {
        float o = 0.f;
        const float4* __restrict__ wap = (const float4*)WuT4 + k;
        #pragma unroll 4
        for (int q = 0; q < 32; ++q) {
            const float4 wa = wap[q * 128];
            const float4 wb = wap[(32 + q) * 128];
            const float4 h4 = *(const float4*)&h_s[jl][4 * q];
            const float4 m4 = *(const float4*)&ms_s[jl][4 * q];
            o += h4.x * wa.x + h4.y * wa.y + h4.z * wa.z + h4.w * wa.w
               + m4.x * wb.x + m4.y * wb.y + m4.z * wb.z + m4.w * wb.w;
        }
        out[(size_t)(b * NN + jbase + jl) * DD + k] = o + bu[k];
    }
}

extern "C" void kernel_launch(void* const* d_in, const int* in_sizes, int n_in,
                              void* d_out, int out_size, void* d_ws, size_t ws_size,
                              hipStream_t stream) {
    const float* h   = (const float*)d_in[0];
    const float* adj = (const float*)d_in[1];
    const float* e   = (const float*)d_in[2];
    const float* Wm  = (const float*)d_in[3];
    const float* bm  = (const float*)d_in[4];
    const float* Wu  = (const float*)d_in[5];
    const float* bu  = (const float*)d_in[6];
    float* out  = (float*)d_out;
    float* es   = (float*)d_out;               // alias: fuse block reads only rows it overwrites
    float* WmT4 = (float*)d_ws;                // 384*128 floats
    float* WuT4 = WmT4 + 384 * 128;            // 256*128 floats
    float* partial = WuT4 + 256 * 128;         // 1024*2048 float4 = 32 MB

    stage1_kernel<<<BB * 64, 256, 0, stream>>>(e, adj, partial, Wm, Wu, WmT4, WuT4);
    stage2_kernel<<<256, 256, 0, stream>>>(partial, es);
    fuse_kernel<<<BB * (NN / 8), 1024, 0, stream>>>(h, adj, es, WmT4, bm, WuT4, bu, out);
}

// Round 9
// 44.211 us; speedup vs baseline: 1.4416x; 1.4416x over previous
//
#include <hip/hip_runtime.h>

#define BB 16
#define NN 128
#define DD 128

// K1: es[b,j,d] = sum_i adj[b,i,j]*e[b,i,j,d].  One block per (b,j), 2048
// blocks -> 8 blocks/CU, 32 waves/CU. PREDICATED loads: adj==0 (~50%) skips
// the 512-B fragment entirely (predicate is LDS-resident, branch resolves
// without waiting on memory). 16 i's per 32-lane group, unrolled.
// Side job (first 320 blocks): float4-interleaved weight transposes.
// es aliases d_out (each fuse block later reads only rows it overwrites).
__global__ __launch_bounds__(256) void es_kernel(const float* __restrict__ e,
                                                 const float* __restrict__ adj,
                                                 float* __restrict__ es,
                                                 const float* __restrict__ Wm,
                                                 const float* __restrict__ Wu,
                                                 float* __restrict__ WmT4,
                                                 float* __restrict__ WuT4) {
    const int bj = blockIdx.x;          // b*128 + j
    const int t = threadIdx.x;

    if (bj < 320) {                     // 320*256 = 384*128 + 256*128
        const int idx = bj * 256 + t;
        if (idx < 384 * 128) {
            const int k = idx / 384, dcol = idx % 384;
            WmT4[((dcol >> 2) * 128 + k) * 4 + (dcol & 3)] = Wm[idx];
        } else {
            const int o = idx - 384 * 128;
            const int k = o / 256, dcol = o % 256;
            WuT4[((dcol >> 2) * 128 + k) * 4 + (dcol & 3)] = Wu[o];
        }
    }

    const int b = bj >> 7, j = bj & 127;
    __shared__ float adj_s[NN];
    __shared__ float4 red[8][32];
    if (t < NN) adj_s[t] = adj[(size_t)(b * NN + t) * NN + j];
    __syncthreads();

    const int d4 = t & 31, ig = t >> 5;          // 8 groups x 16 i's
    const float4* __restrict__ e4 =
        (const float4*)e + ((size_t)(b * NN) * NN + j) * 32 + d4;
    const int i0 = ig * 16;
    float4 acc = make_float4(0.f, 0.f, 0.f, 0.f);
    #pragma unroll
    for (int ii = 0; ii < 16; ++ii) {
        const float a = adj_s[i0 + ii];
        if (a != 0.0f) {                          // skip fetch of zero fragments
            const float4 v = e4[(size_t)(i0 + ii) * (NN * 32)];
            acc.x += a * v.x; acc.y += a * v.y;
            acc.z += a * v.z; acc.w += a * v.w;
        }
    }
    red[ig][d4] = acc;
    __syncthreads();
    if (t < 32) {
        float4 s = red[0][t];
        #pragma unroll
        for (int r = 1; r < 8; ++r) {
            const float4 v = red[r][t];
            s.x += v.x; s.y += v.y; s.z += v.z; s.w += v.w;
        }
        ((float4*)es)[(size_t)bj * 32 + t] = s;
    }
}

// K2: fused small GEMMs. Block = (b, 8 j's), 1024 threads (16 waves, 1
// block/CU). Thread slice jl = t>>7 owns one j. Weight reads via WmT4/WuT4
// float4-interleaved (coalesced across lanes).
__global__ __launch_bounds__(1024) void fuse_kernel(
    const float* __restrict__ h, const float* __restrict__ adj,
    const float* __restrict__ es, const float* __restrict__ WmT4,
    const float* __restrict__ bm, const float* __restrict__ WuT4,
    const float* __restrict__ bu, float* __restrict__ out) {
    const int blk = blockIdx.x;
    const int b = blk >> 4;
    const int jbase = (blk & 15) * 8;
    const int t = threadIdx.x;

    __shared__ float adj_s[8][NN];
    __shared__ float h_s[8][DD];
    __shared__ float es_s[8][DD];
    __shared__ float ah_s[8][DD];
    __shared__ float ms_s[8][DD];
    __shared__ float deg_s[8];

    {   // staging: one pass each, 1024 threads
        const int jj = t >> 7, d0 = t & 127;
        h_s[jj][d0]  = h [(size_t)(b * NN + jbase + jj) * DD + d0];
        es_s[jj][d0] = es[(size_t)(b * NN + jbase + jj) * DD + d0];
        const int i = t >> 3, j2 = t & 7;
        adj_s[j2][i] = adj[(size_t)(b * NN + i) * NN + jbase + j2];
    }
    __syncthreads();

    const int k = t & 127, jl = t >> 7;       // jl = 0..7, one j per slice

    if (t < 256) {                            // deg[jj] = sum_i adj[i][jj]
        const int jj = t >> 5, l = t & 31;
        float s = adj_s[jj][l] + adj_s[jj][l + 32] + adj_s[jj][l + 64] + adj_s[jj][l + 96];
        #pragma unroll
        for (int off = 16; off; off >>= 1) s += __shfl_xor(s, off);
        if (l == 0) deg_s[jj] = s;
    }

    // C: ah[jl][k] = sum_i adj[i][jl]*h[b,i,k]  (h coalesced across lanes)
    {
        float a0 = 0.f;
        const float* __restrict__ hp = h + (size_t)b * NN * DD + k;
        #pragma unroll 8
        for (int m = 0; m < 32; ++m) {
            const float4 aA = *(const float4*)&adj_s[jl][4 * m];
            const float h0 = hp[(size_t)(4 * m + 0) * DD];
            const float h1 = hp[(size_t)(4 * m + 1) * DD];
            const float h2 = hp[(size_t)(4 * m + 2) * DD];
            const float h3 = hp[(size_t)(4 * m + 3) * DD];
            a0 += aA.x * h0 + aA.y * h1 + aA.z * h2 + aA.w * h3;
        }
        ah_s[jl][k] = a0;
    }
    __syncthreads();

    // D: msum[jl][k]
    {
        float pa = 0.f, ph = 0.f, pe = 0.f;
        const float4* __restrict__ w1p = (const float4*)WmT4 + k;
        #pragma unroll 4
        for (int q = 0; q < 32; ++q) {
            const float4 w1 = w1p[q * 128];
            const float4 w2 = w1p[(32 + q) * 128];
            const float4 w3 = w1p[(64 + q) * 128];
            const float4 ah4 = *(const float4*)&ah_s[jl][4 * q];
            const float4 h4  = *(const float4*)&h_s[jl][4 * q];
            const float4 e4v = *(const float4*)&es_s[jl][4 * q];
            pa += ah4.x * w1.x + ah4.y * w1.y + ah4.z * w1.z + ah4.w * w1.w;
            ph += h4.x  * w2.x + h4.y  * w2.y + h4.z  * w2.z + h4.w  * w2.w;
            pe += e4v.x * w3.x + e4v.y * w3.y + e4v.z * w3.z + e4v.w * w3.w;
        }
        ms_s[jl][k] = pa + pe + deg_s[jl] * (ph + bm[k]);
    }
    __syncthreads();

    // E: out = h·WuA^T + msum·WuB^T + bu
    {
        float o = 0.f;
        const float4* __restrict__ wap = (const float4*)WuT4 + k;
        #pragma unroll 4
        for (int q = 0; q < 32; ++q) {
            const float4 wa = wap[q * 128];
            const float4 wb = wap[(32 + q) * 128];
            const float4 h4 = *(const float4*)&h_s[jl][4 * q];
            const float4 m4 = *(const float4*)&ms_s[jl][4 * q];
            o += h4.x * wa.x + h4.y * wa.y + h4.z * wa.z + h4.w * wa.w
               + m4.x * wb.x + m4.y * wb.y + m4.z * wb.z + m4.w * wb.w;
        }
        out[(size_t)(b * NN + jbase + jl) * DD + k] = o + bu[k];
    }
}

extern "C" void kernel_launch(void* const* d_in, const int* in_sizes, int n_in,
                              void* d_out, int out_size, void* d_ws, size_t ws_size,
                              hipStream_t stream) {
    const float* h   = (const float*)d_in[0];
    const float* adj = (const float*)d_in[1];
    const float* e   = (const float*)d_in[2];
    const float* Wm  = (const float*)d_in[3];
    const float* bm  = (const float*)d_in[4];
    const float* Wu  = (const float*)d_in[5];
    const float* bu  = (const float*)d_in[6];
    float* out  = (float*)d_out;
    float* es   = (float*)d_out;               // alias: fuse block reads only rows it overwrites
    float* WmT4 = (float*)d_ws;                // 384*128 floats
    float* WuT4 = WmT4 + 384 * 128;            // 256*128 floats (320 KB total)

    es_kernel<<<BB * NN, 256, 0, stream>>>(e, adj, es, Wm, Wu, WmT4, WuT4);
    fuse_kernel<<<BB * (NN / 8), 1024, 0, stream>>>(h, adj, es, WmT4, bm, WuT4, bu, out);
}

// Round 10
// 38.081 us; speedup vs baseline: 1.6737x; 1.1610x over previous
//
#include <hip/hip_runtime.h>
#include <hip/hip_bf16.h>

#define BB 16
#define NN 128
#define DD 128

typedef __attribute__((ext_vector_type(8))) short s8v;   // 8 bf16 (4 VGPRs)
typedef __attribute__((ext_vector_type(4))) float f4v;   // MFMA C/D

__device__ __forceinline__ unsigned short f2bf(float f) {
    __hip_bfloat16 b = __float2bfloat16(f);
    return *reinterpret_cast<unsigned short*>(&b);
}

// prep: BT[k][rho] (bf16, 128x512): rho 0-127 = WuA^T (Wu[k,d]);
// 128-255 = G1T[d]=sum_kk Wm[kk,d]Wu[k,128+kk]; 256-383 = G3T (off 256);
// 384-511 = G2T (off 128). Plus bmWu[k] (fp32) and hbf (h cast bf16).
__global__ __launch_bounds__(256) void prep_kernel(
    const float* __restrict__ h, const float* __restrict__ Wm,
    const float* __restrict__ bm, const float* __restrict__ Wu,
    unsigned short* __restrict__ BT, float* __restrict__ bmWu,
    unsigned short* __restrict__ hbf) {
    const int g = blockIdx.x, t = threadIdx.x;
    if (g < 48) {
        __shared__ float WuB_s[128][129];           // [kk][k], padded
        for (int p = 0; p < 64; ++p) {
            const int x = p * 256 + t;              // k = x>>7, kk = x&127
            WuB_s[x & 127][x >> 7] = Wu[(x >> 7) * 256 + 128 + (x & 127)];
        }
        __syncthreads();
        const int m = g >> 4, dc = g & 15;
        const int off   = (m == 0) ? 0   : (m == 1) ? 256 : 128;
        const int rbase = (m == 0) ? 128 : (m == 1) ? 256 : 384;
        const int k = t & 127, dh = t >> 7;
        const int d0 = dc * 8 + dh * 4;
        float a0 = 0, a1 = 0, a2 = 0, a3 = 0;
        for (int kk = 0; kk < 128; ++kk) {
            const float wu = WuB_s[kk][k];
            const float* wmp = Wm + kk * 384 + off + d0;
            a0 += wmp[0] * wu; a1 += wmp[1] * wu;
            a2 += wmp[2] * wu; a3 += wmp[3] * wu;
        }
        unsigned short* bp = BT + (size_t)k * 512 + rbase + d0;
        bp[0] = f2bf(a0); bp[1] = f2bf(a1); bp[2] = f2bf(a2); bp[3] = f2bf(a3);
    } else if (g == 48) {
        for (int p = 0; p < 64; ++p) {
            const int x = p * 256 + t, k = x >> 7, d = x & 127;
            BT[(size_t)k * 512 + d] = f2bf(Wu[k * 256 + d]);
        }
        if (t < 128) {
            float s = 0.f;
            for (int kk = 0; kk < 128; ++kk) s += bm[kk] * Wu[t * 256 + 128 + kk];
            bmWu[t] = s;
        }
    } else {                                        // g = 49..56: hbf cast
        const int bi = g - 49;
        const float4* h4 = (const float4*)h;
        uint2* hb2 = (uint2*)hbf;
        for (int p = 0; p < 32; ++p) {
            const int i4 = bi * 8192 + p * 256 + t;
            const float4 v = h4[i4];
            hb2[i4] = make_uint2((unsigned)f2bf(v.x) | ((unsigned)f2bf(v.y) << 16),
                                 (unsigned)f2bf(v.z) | ((unsigned)f2bf(v.w) << 16));
        }
    }
}

// es: es[b,j,d] = sum_i adj[b,i,j]*e[b,i,j,d] -> bf16 in ws. R9-proven body.
__global__ __launch_bounds__(256) void es_kernel(const float* __restrict__ e,
                                                 const float* __restrict__ adj,
                                                 unsigned short* __restrict__ esbf) {
    const int bj = blockIdx.x, t = threadIdx.x;
    const int b = bj >> 7, j = bj & 127;
    __shared__ float adj_s[NN];
    __shared__ float4 red[8][32];
    if (t < NN) adj_s[t] = adj[(size_t)(b * NN + t) * NN + j];
    __syncthreads();
    const int d4 = t & 31, ig = t >> 5;
    const float4* __restrict__ e4 =
        (const float4*)e + ((size_t)(b * NN) * NN + j) * 32 + d4;
    const int i0 = ig * 16;
    float4 acc = make_float4(0.f, 0.f, 0.f, 0.f);
    #pragma unroll
    for (int ii = 0; ii < 16; ++ii) {
        const float a = adj_s[i0 + ii];
        if (a != 0.0f) {
            const float4 v = e4[(size_t)(i0 + ii) * (NN * 32)];
            acc.x += a * v.x; acc.y += a * v.y;
            acc.z += a * v.z; acc.w += a * v.w;
        }
    }
    red[ig][d4] = acc;
    __syncthreads();
    if (t < 32) {
        float4 s = red[0][t];
        #pragma unroll
        for (int r = 1; r < 8; ++r) {
            const float4 v = red[r][t];
            s.x += v.x; s.y += v.y; s.z += v.z; s.w += v.w;
        }
        ((uint2*)esbf)[(size_t)bj * 32 + t] =
            make_uint2((unsigned)f2bf(s.x) | ((unsigned)f2bf(s.y) << 16),
                       (unsigned)f2bf(s.z) | ((unsigned)f2bf(s.w) << 16));
    }
}

// ah: AH[b,j,k] = sum_i adj[i,j]*h[b,i,k] (fp32, R9-proven C-phase) -> bf16;
// also deg[b,j]. Block = (b, 8 j's), 1024 threads.
__global__ __launch_bounds__(1024) void ah_kernel(
    const float* __restrict__ h, const float* __restrict__ adj,
    unsigned short* __restrict__ AHbf, float* __restrict__ deg) {
    const int blk = blockIdx.x;
    const int b = blk >> 4, jbase = (blk & 15) * 8;
    const int t = threadIdx.x;
    __shared__ float adj_s[8][NN];
    {
        const int i = t >> 3, j2 = t & 7;
        adj_s[j2][i] = adj[(size_t)(b * NN + i) * NN + jbase + j2];
    }
    __syncthreads();
    if (t < 256) {
        const int jj = t >> 5, l = t & 31;
        float s = adj_s[jj][l] + adj_s[jj][l + 32] + adj_s[jj][l + 64] + adj_s[jj][l + 96];
        #pragma unroll
        for (int off = 16; off; off >>= 1) s += __shfl_xor(s, off);
        if (l == 0) deg[b * NN + jbase + jj] = s;
    }
    const int k = t & 127, jl = t >> 7;
    float a0 = 0.f;
    const float* __restrict__ hp = h + (size_t)b * NN * DD + k;
    #pragma unroll 8
    for (int m = 0; m < 32; ++m) {
        const float4 aA = *(const float4*)&adj_s[jl][4 * m];
        const float h0 = hp[(size_t)(4 * m + 0) * DD];
        const float h1 = hp[(size_t)(4 * m + 1) * DD];
        const float h2 = hp[(size_t)(4 * m + 2) * DD];
        const float h3 = hp[(size_t)(4 * m + 3) * DD];
        a0 += aA.x * h0 + aA.y * h1 + aA.z * h2 + aA.w * h3;
    }
    AHbf[(size_t)(b * NN + jbase + jl) * DD + k] = f2bf(a0);
}

// out: MFMA GEMM. Block = (row-tile 32, k-tile 32): 64x4 = 256 blocks.
// acc1 = [h|AH|es]·[WuAT;G1T;G3T] (K=384); acc2 = h·G2T (K=128, shared A-frags).
// out = acc1 + deg*acc2 + deg*bmWu + bu   (deg exact fp32 in epilogue).
__global__ __launch_bounds__(256) void out_kernel(
    const unsigned short* __restrict__ hbf, const unsigned short* __restrict__ AHbf,
    const unsigned short* __restrict__ esbf, const unsigned short* __restrict__ BT,
    const float* __restrict__ deg, const float* __restrict__ bmWu,
    const float* __restrict__ bu, float* __restrict__ out) {
    const int rt = blockIdx.x >> 2, ct = blockIdx.x & 3;
    const int t = threadIdx.x;
    const int l = t & 63, wid = t >> 6, mw = wid >> 1, nw = wid & 1;
    __shared__ unsigned short A_s[32][72], B_s[32][72], B2_s[32][72];
    f4v acc1 = {0.f, 0.f, 0.f, 0.f};
    f4v acc2 = {0.f, 0.f, 0.f, 0.f};
    const int rA = t >> 3, cb = t & 7;          // staging: 32 rows x 8 col-blocks
    const int arow = mw * 16 + (l & 15);
    const int brow = nw * 16 + (l & 15);
    const int lg = l >> 4;
    for (int c = 0; c < 6; ++c) {
        __syncthreads();
        const unsigned short* src = (c < 2) ? hbf : (c < 4) ? AHbf : esbf;
        const int col0 = (c & 1) * 64;
        const int rowg = rt * 32 + rA;
        *(s8v*)&A_s[rA][cb * 8] = *(const s8v*)&src[(size_t)rowg * 128 + col0 + cb * 8];
        *(s8v*)&B_s[rA][cb * 8] =
            *(const s8v*)&BT[(size_t)(ct * 32 + rA) * 512 + c * 64 + cb * 8];
        if (c < 2)
            *(s8v*)&B2_s[rA][cb * 8] =
                *(const s8v*)&BT[(size_t)(ct * 32 + rA) * 512 + 384 + c * 64 + cb * 8];
        __syncthreads();
        #pragma unroll
        for (int kit = 0; kit < 2; ++kit) {
            const s8v a  = *(const s8v*)&A_s[arow][kit * 32 + lg * 8];
            const s8v bb = *(const s8v*)&B_s[brow][kit * 32 + lg * 8];
            acc1 = __builtin_amdgcn_mfma_f32_16x16x32_bf16(a, bb, acc1, 0, 0, 0);
            if (c < 2) {
                const s8v b2 = *(const s8v*)&B2_s[brow][kit * 32 + lg * 8];
                acc2 = __builtin_amdgcn_mfma_f32_16x16x32_bf16(a, b2, acc2, 0, 0, 0);
            }
        }
    }
    const int colk = ct * 32 + nw * 16 + (l & 15);
    const float bmv = bmWu[colk], buv = bu[colk];
    #pragma unroll
    for (int r = 0; r < 4; ++r) {
        const int rowg = rt * 32 + mw * 16 + (l >> 4) * 4 + r;
        const float dg = deg[rowg];
        out[(size_t)rowg * 128 + colk] = acc1[r] + dg * acc2[r] + dg * bmv + buv;
    }
}

extern "C" void kernel_launch(void* const* d_in, const int* in_sizes, int n_in,
                              void* d_out, int out_size, void* d_ws, size_t ws_size,
                              hipStream_t stream) {
    const float* h   = (const float*)d_in[0];
    const float* adj = (const float*)d_in[1];
    const float* e   = (const float*)d_in[2];
    const float* Wm  = (const float*)d_in[3];
    const float* bm  = (const float*)d_in[4];
    const float* Wu  = (const float*)d_in[5];
    const float* bu  = (const float*)d_in[6];
    float* out = (float*)d_out;

    float* ws = (float*)d_ws;                         // ~1.7 MB used (<< proven 32 MB)
    unsigned short* BT   = (unsigned short*)ws;       // 128x512 bf16
    float*          bmWu = ws + 32768;                // 128 f32
    float*          deg  = ws + 32896;                // 2048 f32
    unsigned short* hbf  = (unsigned short*)(ws + 34944);   // 2048x128 bf16
    unsigned short* AHbf = (unsigned short*)(ws + 166016);  // 2048x128 bf16
    unsigned short* esbf = (unsigned short*)(ws + 297088);  // 2048x128 bf16

    prep_kernel<<<57, 256, 0, stream>>>(h, Wm, bm, Wu, BT, bmWu, hbf);
    es_kernel<<<BB * NN, 256, 0, stream>>>(e, adj, esbf);
    ah_kernel<<<BB * (NN / 8), 1024, 0, stream>>>(h, adj, AHbf, deg);
    out_kernel<<<256, 256, 0, stream>>>(hbf, AHbf, esbf, BT, deg, bmWu, bu, out);
}